// Round 2
// 673.643 us; speedup vs baseline: 1.0251x; 1.0251x over previous
//
#include <hip/hip_runtime.h>
#include <math.h>

// Problem constants
#define Bsz 64
#define Tsz 4096
#define Dsz 512

// Phase-1 geometry: register-streaming, no LDS staging.
#define THREADS 256
#define NWAVES (THREADS / 64)          // 4 waves per block
#define ROWS_PER_WAVE 16
#define CH (NWAVES * ROWS_PER_WAVE)    // 64 T-rows per block
#define CHUNKS (Tsz / CH)              // 64 chunks along T

// Phase 1: each wave streams 16 full rows of x[b] through registers.
// A wave's 64 lanes x 8 cols cover a full D=512 row, so one load serves
// both the dot product (butterfly shuffle-reduce across the wave) and
// the weighted column accumulation:
//   num[b,d] += sum_t exp(tanh(x_t.W + bias[t])) * x[b,t,d]
//   den[b]   += sum_t exp(tanh(...))
// exp needs no max-subtraction: tanh bounds the logit to [-1,1].
__global__ __launch_bounds__(THREADS) void attn_phase1(
    const float* __restrict__ x, const float* __restrict__ W,
    const float* __restrict__ bias, float* __restrict__ num,
    float* __restrict__ den) {
  const int tid  = threadIdx.x;
  const int lane = tid & 63;
  const int wave = tid >> 6;
  const int s = blockIdx.x;            // chunk index along T
  const int b = blockIdx.y;            // batch

  // W fragment: lane owns cols 8*lane .. 8*lane+7
  const float4* W4 = (const float4*)W;
  const float4 w0 = W4[2 * lane];
  const float4 w1 = W4[2 * lane + 1];

  const int row0 = s * CH + wave * ROWS_PER_WAVE;
  const float4* xr = (const float4*)(x + ((size_t)b * Tsz + row0) * Dsz);
  const float* brow = bias + row0;

  float4 acc0 = make_float4(0.f, 0.f, 0.f, 0.f);
  float4 acc1 = make_float4(0.f, 0.f, 0.f, 0.f);
  float wsum = 0.f;

#pragma unroll 2
  for (int i = 0; i < ROWS_PER_WAVE; ++i) {
    // Coalesced: wave reads the whole 2 KiB row (2x global_load_dwordx4/lane)
    const float4 a0 = xr[(size_t)i * (Dsz / 4) + 2 * lane];
    const float4 a1 = xr[(size_t)i * (Dsz / 4) + 2 * lane + 1];
    const float bi = brow[i];          // scalar load, issues early

    float p = a0.x * w0.x + a0.y * w0.y + a0.z * w0.z + a0.w * w0.w
            + a1.x * w1.x + a1.y * w1.y + a1.z * w1.z + a1.w * w1.w;
#pragma unroll
    for (int off = 32; off >= 1; off >>= 1) p += __shfl_xor(p, off, 64);

    const float wgt = expf(tanhf(p + bi));   // identical in all lanes
    wsum += wgt;
    acc0.x += wgt * a0.x; acc0.y += wgt * a0.y;
    acc0.z += wgt * a0.z; acc0.w += wgt * a0.w;
    acc1.x += wgt * a1.x; acc1.y += wgt * a1.y;
    acc1.z += wgt * a1.z; acc1.w += wgt * a1.w;
  }

  // Cross-wave reduce in LDS (8 KiB), then one atomicAdd per column.
  __shared__ float red[NWAVES][Dsz];
  __shared__ float redw[NWAVES];
  float4* dst = (float4*)&red[wave][0];
  dst[2 * lane]     = acc0;
  dst[2 * lane + 1] = acc1;
  if (lane == 0) redw[wave] = wsum;   // wsum identical across lanes
  __syncthreads();

#pragma unroll
  for (int c = tid; c < Dsz; c += THREADS) {   // consecutive tid -> conflict-free
    float v = 0.f;
#pragma unroll
    for (int wv = 0; wv < NWAVES; ++wv) v += red[wv][c];
    atomicAdd(&num[(size_t)b * Dsz + c], v);
  }
  if (tid == 0) {
    float dv = 0.f;
#pragma unroll
    for (int wv = 0; wv < NWAVES; ++wv) dv += redw[wv];
    atomicAdd(&den[b], dv);
  }
}

// Phase 2: out[b,d] = num[b,d] / den[b]
__global__ __launch_bounds__(512) void attn_phase2(
    const float* __restrict__ num, const float* __restrict__ den,
    float* __restrict__ out) {
  const int i = blockIdx.x * blockDim.x + threadIdx.x;  // 0..32767
  const int b = i >> 9;
  out[i] = num[i] / den[b];
}

extern "C" void kernel_launch(void* const* d_in, const int* in_sizes, int n_in,
                              void* d_out, int out_size, void* d_ws, size_t ws_size,
                              hipStream_t stream) {
  const float* x    = (const float*)d_in[0];  // [B,T,D]
  const float* W    = (const float*)d_in[1];  // [D,1]
  const float* bias = (const float*)d_in[2];  // [T,1]
  float* num = (float*)d_ws;                  // [B*D]
  float* den = num + (size_t)Bsz * Dsz;       // [B]

  // ws is poisoned 0xAA before every launch -> zero the accumulators
  hipMemsetAsync(d_ws, 0, ((size_t)Bsz * Dsz + Bsz) * sizeof(float), stream);

  dim3 g1(CHUNKS, Bsz);
  attn_phase1<<<g1, THREADS, 0, stream>>>(x, W, bias, num, den);
  attn_phase2<<<Bsz, Dsz, 0, stream>>>(num, den, (float*)d_out);
}

// Round 3
// 664.295 us; speedup vs baseline: 1.0395x; 1.0141x over previous
//
#include <hip/hip_runtime.h>
#include <math.h>

// Problem constants
#define Bsz 64
#define Tsz 4096
#define Dsz 512

// Phase-1 geometry: register-streaming, no LDS staging.
#define THREADS 256
#define NWAVES (THREADS / 64)          // 4 waves per block
#define ROWS_PER_WAVE 16
#define CH (NWAVES * ROWS_PER_WAVE)    // 64 T-rows per block
#define CHUNKS (Tsz / CH)              // 64 chunks along T

typedef float vf4 __attribute__((ext_vector_type(4)));

// w = exp(tanh(q)), branch-free: tanh(q) = 1 - 2/(e^{2q}+1).
// Large q: e^{2q}=inf -> rcp=0 -> t=1. Very negative q: e^{2q}=0 -> t=-1.
// No NaN paths; ~10 VALU ops vs libm's branchy tanhf+expf.
__device__ __forceinline__ float fast_weight(float q) {
  const float e2q = __expf(2.f * q);                       // v_exp_f32 based
  const float t = 1.f - 2.f * __builtin_amdgcn_rcpf(e2q + 1.f);
  return __expf(t);
}

// Phase 1: each wave streams 16 full rows of x[b] through registers.
// One load serves both the dot product (butterfly shuffle-reduce) and the
// weighted column accumulation:
//   num[b,d] += sum_t exp(tanh(x_t.W + bias[t])) * x[b,t,d]
//   den[b]   += sum_t exp(tanh(...))
// exp needs no max-subtraction: tanh bounds the logit to [-1,1].
__global__ __launch_bounds__(THREADS, 4) void attn_phase1(
    const float* __restrict__ x, const float* __restrict__ W,
    const float* __restrict__ bias, float* __restrict__ num,
    float* __restrict__ den) {
  const int tid  = threadIdx.x;
  const int lane = tid & 63;
  const int wave = tid >> 6;
  const int s = blockIdx.x;            // chunk index along T
  const int b = blockIdx.y;            // batch

  // W fragment: lane owns cols 8*lane .. 8*lane+7
  const vf4* W4 = (const vf4*)W;
  const vf4 w0 = W4[2 * lane];
  const vf4 w1 = W4[2 * lane + 1];

  const int row0 = s * CH + wave * ROWS_PER_WAVE;
  const vf4* __restrict__ xr = (const vf4*)(x + ((size_t)b * Tsz + row0) * Dsz);
  const float* brow = bias + row0;

  vf4 acc0 = (vf4)(0.f);
  vf4 acc1 = (vf4)(0.f);
  float wsum = 0.f;

#pragma unroll 4
  for (int i = 0; i < ROWS_PER_WAVE; ++i) {
    // Coalesced, non-temporal (x has zero reuse): 2x global_load_dwordx4 nt
    const vf4 a0 = __builtin_nontemporal_load(&xr[(size_t)i * (Dsz / 4) + 2 * lane]);
    const vf4 a1 = __builtin_nontemporal_load(&xr[(size_t)i * (Dsz / 4) + 2 * lane + 1]);
    const float bi = brow[i];

    float p = a0.x * w0.x + a0.y * w0.y + a0.z * w0.z + a0.w * w0.w
            + a1.x * w1.x + a1.y * w1.y + a1.z * w1.z + a1.w * w1.w;
#pragma unroll
    for (int off = 32; off >= 1; off >>= 1) p += __shfl_xor(p, off, 64);

    const float wgt = fast_weight(p + bi);   // identical in all lanes
    wsum += wgt;
    acc0.x += wgt * a0.x; acc0.y += wgt * a0.y;
    acc0.z += wgt * a0.z; acc0.w += wgt * a0.w;
    acc1.x += wgt * a1.x; acc1.y += wgt * a1.y;
    acc1.z += wgt * a1.z; acc1.w += wgt * a1.w;
  }

  // Cross-wave reduce in LDS (8 KiB), then one atomicAdd per column.
  __shared__ float red[NWAVES][Dsz];
  __shared__ float redw[NWAVES];
  vf4* dst = (vf4*)&red[wave][0];
  dst[2 * lane]     = acc0;
  dst[2 * lane + 1] = acc1;
  if (lane == 0) redw[wave] = wsum;   // wsum identical across lanes
  __syncthreads();

#pragma unroll
  for (int c = tid; c < Dsz; c += THREADS) {   // consecutive tid -> conflict-free
    float v = 0.f;
#pragma unroll
    for (int wv = 0; wv < NWAVES; ++wv) v += red[wv][c];
    atomicAdd(&num[(size_t)b * Dsz + c], v);
  }
  if (tid == 0) {
    float dv = 0.f;
#pragma unroll
    for (int wv = 0; wv < NWAVES; ++wv) dv += redw[wv];
    atomicAdd(&den[b], dv);
  }
}

// Phase 2: out[b,d] = num[b,d] / den[b]
__global__ __launch_bounds__(512) void attn_phase2(
    const float* __restrict__ num, const float* __restrict__ den,
    float* __restrict__ out) {
  const int i = blockIdx.x * blockDim.x + threadIdx.x;  // 0..32767
  const int b = i >> 9;
  out[i] = num[i] / den[b];
}

extern "C" void kernel_launch(void* const* d_in, const int* in_sizes, int n_in,
                              void* d_out, int out_size, void* d_ws, size_t ws_size,
                              hipStream_t stream) {
  const float* x    = (const float*)d_in[0];  // [B,T,D]
  const float* W    = (const float*)d_in[1];  // [D,1]
  const float* bias = (const float*)d_in[2];  // [T,1]
  float* num = (float*)d_ws;                  // [B*D]
  float* den = num + (size_t)Bsz * Dsz;       // [B]

  // ws is poisoned 0xAA before every launch -> zero the accumulators
  hipMemsetAsync(d_ws, 0, ((size_t)Bsz * Dsz + Bsz) * sizeof(float), stream);

  dim3 g1(CHUNKS, Bsz);
  attn_phase1<<<g1, THREADS, 0, stream>>>(x, W, bias, num, den);
  attn_phase2<<<Bsz, Dsz, 0, stream>>>(num, den, (float*)d_out);
}

// Round 4
// 656.130 us; speedup vs baseline: 1.0524x; 1.0124x over previous
//
#include <hip/hip_runtime.h>
#include <math.h>

// Problem constants
#define Bsz 64
#define Tsz 4096
#define Dsz 512

// Phase-1 geometry: register-streaming, no LDS staging.
#define THREADS 256
#define NWAVES (THREADS / 64)          // 4 waves per block
#define ROWS_PER_WAVE 16
#define CH (NWAVES * ROWS_PER_WAVE)    // 64 T-rows per block
#define CHUNKS (Tsz / CH)              // 64 chunks along T

typedef float vf4 __attribute__((ext_vector_type(4)));

// w = exp(tanh(q)), branch-free: tanh(q) = 1 - 2/(e^{2q}+1).
// Large q: e^{2q}=inf -> rcp=0 -> t=1. Very negative q: e^{2q}=0 -> t=-1.
__device__ __forceinline__ float fast_weight(float q) {
  const float e2q = __expf(2.f * q);                       // v_exp_f32 based
  const float t = 1.f - 2.f * __builtin_amdgcn_rcpf(e2q + 1.f);
  return __expf(t);
}

// Phase 1: each wave streams 16 full rows of x[b] through registers.
// Lane l owns float4 columns {l, 64+l}: each global_load_dwordx4 is a
// DENSE 1 KiB wave transaction (64 lanes x 16 B contiguous) -- every
// 128 B line is fully covered by a single instruction (safe with nt).
// One load serves both the dot product (butterfly shuffle-reduce) and
// the weighted column accumulation:
//   num[b,d] += sum_t exp(tanh(x_t.W + bias[t])) * x[b,t,d]
//   den[b]   += sum_t exp(tanh(...))
// exp needs no max-subtraction: tanh bounds the logit to [-1,1].
__global__ __launch_bounds__(THREADS, 4) void attn_phase1(
    const float* __restrict__ x, const float* __restrict__ W,
    const float* __restrict__ bias, float* __restrict__ num,
    float* __restrict__ den) {
  const int tid  = threadIdx.x;
  const int lane = tid & 63;
  const int wave = tid >> 6;
  const int s = blockIdx.x;            // chunk index along T
  const int b = blockIdx.y;            // batch

  // W fragment matching the load pattern: float4 l and float4 64+l
  const vf4* W4 = (const vf4*)W;
  const vf4 w0 = W4[lane];
  const vf4 w1 = W4[64 + lane];

  const int row0 = s * CH + wave * ROWS_PER_WAVE;
  const vf4* __restrict__ xr = (const vf4*)(x + ((size_t)b * Tsz + row0) * Dsz);
  const float* brow = bias + row0;

  vf4 acc0 = (vf4)(0.f);
  vf4 acc1 = (vf4)(0.f);
  float wsum = 0.f;

#pragma unroll 4
  for (int i = 0; i < ROWS_PER_WAVE; ++i) {
    // Two dense 1 KiB wave loads per 2 KiB row, non-temporal (zero reuse)
    const vf4 a0 = __builtin_nontemporal_load(&xr[(size_t)i * 128 + lane]);
    const vf4 a1 = __builtin_nontemporal_load(&xr[(size_t)i * 128 + 64 + lane]);
    const float bi = brow[i];

    float p = a0.x * w0.x + a0.y * w0.y + a0.z * w0.z + a0.w * w0.w
            + a1.x * w1.x + a1.y * w1.y + a1.z * w1.z + a1.w * w1.w;
#pragma unroll
    for (int off = 32; off >= 1; off >>= 1) p += __shfl_xor(p, off, 64);

    const float wgt = fast_weight(p + bi);   // identical in all lanes
    wsum += wgt;
    acc0.x += wgt * a0.x; acc0.y += wgt * a0.y;
    acc0.z += wgt * a0.z; acc0.w += wgt * a0.w;
    acc1.x += wgt * a1.x; acc1.y += wgt * a1.y;
    acc1.z += wgt * a1.z; acc1.w += wgt * a1.w;
  }

  // Cross-wave reduce in LDS (8 KiB), then one atomicAdd per column.
  // Lane l's accs are float4 cols l and 64+l -> store at those indices.
  __shared__ float red[NWAVES][Dsz];
  __shared__ float redw[NWAVES];
  vf4* dst = (vf4*)&red[wave][0];
  dst[lane]      = acc0;
  dst[64 + lane] = acc1;
  if (lane == 0) redw[wave] = wsum;   // wsum identical across lanes
  __syncthreads();

#pragma unroll
  for (int c = tid; c < Dsz; c += THREADS) {   // consecutive tid -> conflict-free
    float v = 0.f;
#pragma unroll
    for (int wv = 0; wv < NWAVES; ++wv) v += red[wv][c];
    atomicAdd(&num[(size_t)b * Dsz + c], v);
  }
  if (tid == 0) {
    float dv = 0.f;
#pragma unroll
    for (int wv = 0; wv < NWAVES; ++wv) dv += redw[wv];
    atomicAdd(&den[b], dv);
  }
}

// Phase 2: out[b,d] = num[b,d] / den[b]
__global__ __launch_bounds__(512) void attn_phase2(
    const float* __restrict__ num, const float* __restrict__ den,
    float* __restrict__ out) {
  const int i = blockIdx.x * blockDim.x + threadIdx.x;  // 0..32767
  const int b = i >> 9;
  out[i] = num[i] / den[b];
}

extern "C" void kernel_launch(void* const* d_in, const int* in_sizes, int n_in,
                              void* d_out, int out_size, void* d_ws, size_t ws_size,
                              hipStream_t stream) {
  const float* x    = (const float*)d_in[0];  // [B,T,D]
  const float* W    = (const float*)d_in[1];  // [D,1]
  const float* bias = (const float*)d_in[2];  // [T,1]
  float* num = (float*)d_ws;                  // [B*D]
  float* den = num + (size_t)Bsz * Dsz;       // [B]

  // ws is poisoned 0xAA before every launch -> zero the accumulators
  hipMemsetAsync(d_ws, 0, ((size_t)Bsz * Dsz + Bsz) * sizeof(float), stream);

  dim3 g1(CHUNKS, Bsz);
  attn_phase1<<<g1, THREADS, 0, stream>>>(x, W, bias, num, den);
  attn_phase2<<<Bsz, Dsz, 0, stream>>>(num, den, (float*)d_out);
}